// Round 6
// baseline (156.976 us; speedup 1.0000x reference)
//
#include <hip/hip_runtime.h>
#include <hip/hip_bf16.h>

#define MPTS 50000
#define NPTS 100000
#define KK 15
#define TM 32      // queries per tile; 16 waves, wave owns 2 -> barrier-free A/B phases
#define NTILES 1563          // ceil(50000/32); last tile half-valid
#define PGRID 256            // persistent grid: 1 block/CU (LDS-limited), 16 waves/CU
#define WTP 1028   // wtw row stride (shorts): 514 b32 = 2 mod 32 -> phase-C A reads uniform banks
#define STP 36     // weight-row stride inside wtw (shorts)
#define STPH 20    // half-h stage row stride (shorts): 40 B rows (8B-aligned)

typedef __attribute__((ext_vector_type(8))) short short8;
typedef __attribute__((ext_vector_type(4))) short short4v;
typedef __attribute__((ext_vector_type(4))) float floatx4;

static __device__ __forceinline__ unsigned short f2bf(float f) {
    __hip_bfloat16 h = __float2bfloat16(f);
    return *reinterpret_cast<unsigned short*>(&h);
}

static __device__ __forceinline__ short8 lds_load8(const unsigned short* p) {
    const short4v a = *(const short4v*)p;
    const short4v b = *(const short4v*)(p + 4);
    short8 r;
    r[0] = a[0]; r[1] = a[1]; r[2] = a[2]; r[3] = a[3];
    r[4] = b[0]; r[5] = b[1]; r[6] = b[2]; r[7] = b[3];
    return r;
}

// ===================== single prep kernel (3 jobs by blockIdx range) ==================
__global__ void prep_all(const float* __restrict__ sf, const float* __restrict__ w,
                         const float* __restrict__ kpts, const float* __restrict__ spt,
                         unsigned short* __restrict__ sfb, float4* __restrict__ spts4,
                         unsigned short* __restrict__ wbf2, float4* __restrict__ kpp) {
    const int b = blockIdx.x, t = threadIdx.x;
    if (b < 782) {
        const int tt = b * 256 + t;
        const int row = tt >> 1, p = tt & 1;          // lane p covers cols 4p+8i+0..3
        if (row < NPTS) {
            const float* base = sf + (size_t)row * 64 + p * 4;
            float4 r = *(const float4*)base;          // i = 0
            {
                ushort4 o;
                o.x = f2bf(r.x); o.y = f2bf(r.y); o.z = f2bf(r.z); o.w = f2bf(r.w);
                *(ushort4*)&sfb[(size_t)row * 64 + p * 4] = o;
            }
#pragma unroll
            for (int i = 1; i < 8; i++) {
                const float4 x = *(const float4*)(base + i * 8);
                ushort4 o;
                o.x = f2bf(x.x); o.y = f2bf(x.y); o.z = f2bf(x.z); o.w = f2bf(x.w);
                *(ushort4*)&sfb[(size_t)row * 64 + i * 8 + p * 4] = o;
                r.x += x.x; r.y += x.y; r.z += x.z; r.w += x.w;   // strict per-j fold
            }
            float sp = (r.x + r.y) + (r.z + r.w);
            sp += __shfl_xor(sp, 1);                  // + other half (commutative: exact)
            if (p == 0) {
                spts4[row] = make_float4(spt[row * 3 + 0], spt[row * 3 + 1],
                                         spt[row * 3 + 2], sp > 0.0f ? 1.0f : -1.0f);
            }
        }
    } else if (b < 814) {
        const int e = (b - 782) * 256 + t;            // 0..8191
        const int lane = e & 63, s = (e >> 6) & 31, wq = e >> 11;
        const int d = wq * 16 + (lane & 15);
        const int lqp = lane >> 4;
        unsigned short o8[8];
#pragma unroll
        for (int j = 0; j < 8; j++) {
            const int kc = s * 32 + lqp * 8 + j;
            const int c = kc >> 4, k = kc & 15;
            o8[j] = (k < KK) ? f2bf(w[k * 4096 + c * 64 + d]) : (unsigned short)0;
        }
#pragma unroll
        for (int j = 0; j < 8; j++) wbf2[(size_t)e * 8 + j] = o8[j];
    } else {
        if (t < 16) *(ushort4*)&sfb[(size_t)NPTS * 64 + t * 4] = make_ushort4(0, 0, 0, 0);
        else if (t == 16) spts4[NPTS] = make_float4(1.0e6f, 1.0e6f, 1.0e6f, -1.0f);
        else if (t >= 32 && t < 32 + KK) {
            const int k = t - 32;
            const float kx = kpts[k * 3 + 0], ky = kpts[k * 3 + 1], kz = kpts[k * 3 + 2];
            kpp[k] = make_float4(-2.f * kx, -2.f * ky, -2.f * kz, kx * kx + ky * ky + kz * kz);
        }
    }
}

// =======================================================================
// Persistent fused kernel: 256 blocks x 1024 threads (16 waves), TM=32.
// Per wave: 2 queries in A/B phases (R2-verified half-stage form).
// Phase C: 16-way split = (d-quadrant q) x (k-quarter kq); each wave does
// both m-halves, so its W'' slice is 8 frags = 32 VGPRs, loaded ONCE per
// persistent block -> wbf2 L2 stream 400 MB -> 8 MB. 4-way split-K reduces
// through dedicated scratch. LDS: stage 40960 + wtw 65792 + inv 128 +
// scratch 24576 = 131456 B -> 1 block/CU = 16 waves/CU (same cap as best).
// =======================================================================
__global__ __launch_bounds__(1024, 4) void kpconv_fused(
    const float* __restrict__ q_points,
    const float4* __restrict__ spts4,         // (N+1) {x,y,z, oksign}, row N = (1e6..,-1)
    const unsigned short* __restrict__ sfb,   // (N+1,64) bf16, row N zero
    const int*   __restrict__ nbr,            // (M,32)
    const unsigned short* __restrict__ wbf2,  // lane-linear B frags (128 KB)
    const float4* __restrict__ kpp,           // (15) {-2kx,-2ky,-2kz,|kp|^2}
    float* __restrict__ out)                  // (M,64)
{
    const int t    = threadIdx.x;
    const int lane = t & 63;
    const int wv   = t >> 6;                  // 0..15
    const int l15  = lane & 15;
    const int lq   = lane >> 4;

    __shared__ __align__(16) unsigned short stage[16][64 * STPH]; // 40960 B
    __shared__ unsigned short wtw[TM * WTP];                      // 65792 B
    __shared__ float inv_lds[TM];                                 // 128 B
    __shared__ __align__(16) float scratch[6144];                 // 24576 B (dedicated)

    const int mw = 2 * wv + (lane >> 5);      // wave-local query (0..31)
    const int h  = lane & 31;
    const int c4 = l15 * 4;

    // phase-C wave role: d-quadrant x k-quarter
    const int q  = wv & 3;
    const int kq = wv >> 2;                   // 0..3

    // ---- W'' slice -> 8 NAMED registers (32 VGPR), once per persistent block ----
    short8 wf0, wf1, wf2, wf3, wf4, wf5, wf6, wf7;
    {
        const unsigned short* const bp =
            wbf2 + ((size_t)((q * 32 + kq * 8) * 64) + lane) * 8;
        wf0 = *(const short8*)(bp + 0 * 512);  wf1 = *(const short8*)(bp + 1 * 512);
        wf2 = *(const short8*)(bp + 2 * 512);  wf3 = *(const short8*)(bp + 3 * 512);
        wf4 = *(const short8*)(bp + 4 * 512);  wf5 = *(const short8*)(bp + 5 * 512);
        wf6 = *(const short8*)(bp + 6 * 512);  wf7 = *(const short8*)(bp + 7 * 512);
    }

    unsigned short* const st = stage[wv];
    const int swzh = (l15 >> 3) << 2;         // flips slot bit2 for rows c >= 32
    const short8 zero8 = {0, 0, 0, 0, 0, 0, 0, 0};

    for (int tile = blockIdx.x; tile < NTILES; tile += PGRID) {
        const int m0 = tile * TM;

        // ---- PREFETCH: neighbor idx + point gather (clamped for tail tile) ----
        const int mwc = min(m0 + mw, MPTS - 1);
        const int idxp = nbr[(size_t)mwc * 32 + h];
        const float4 sp4 = spts4[min(idxp, NPTS)];

        // ---- issue BOTH m feature gathers (16 x 8B, rows paired per lane slot) ----
        ushort4 g[2][8];
#pragma unroll
        for (int mi = 0; mi < 2; mi++) {
            const int mq = min(m0 + 2 * wv + mi, MPTS - 1);
#pragma unroll
            for (int g2 = 0; g2 < 4; g2++) {
                const int r0 = g2 * 8 + lq * 2;
                const int2 ip = *(const int2*)&nbr[(size_t)mq * 32 + r0];
                const int i0 = min(ip.x, NPTS);
                const int i1 = min(ip.y, NPTS);
                g[mi][2 * g2]     = *(const ushort4*)&sfb[(size_t)i0 * 64 + c4];
                g[mi][2 * g2 + 1] = *(const ushort4*)&sfb[(size_t)i1 * 64 + c4];
            }
        }

        // ---- WEIGHTS: kernel-point weights + neighbor count (covers gather latency) ----
        {
            const float rx = sp4.x - q_points[mwc * 3 + 0];
            const float ry = sp4.y - q_points[mwc * 3 + 1];
            const float rz = sp4.z - q_points[mwc * 3 + 2];
            const float r2 = rx * rx + ry * ry + rz * rz;
            unsigned short* wrow = &wtw[mw * WTP];
#pragma unroll
            for (int k = 0; k < KK; k++) {
                const float4 kp = kpp[k];             // wave-uniform -> s_load
                float d2 = kp.w;
                d2 = fmaf(rx, kp.x, d2);
                d2 = fmaf(ry, kp.y, d2);
                d2 = fmaf(rz, kp.z, d2);
                d2 = fmaxf(r2 + d2, 0.0f);            // guard tiny-negative from rounding
                const float wv_ = fmaxf(fmaf(-0.5f, __builtin_amdgcn_sqrtf(d2), 1.0f), 0.0f);
                wrow[k * STP + h] = f2bf(wv_);
            }
            wrow[15 * STP + h] = 0;                   // k-pad row

            const unsigned long long bal = __ballot(sp4.w > 0.0f);
            if (h == 0) {
                const int cnt = __popc((unsigned)(bal >> ((lane >> 5) * 32)));
                inv_lds[mw] = 1.0f / (float)(cnt < 1 ? 1 : cnt);
            }
        }

        // ---- PHASEB: wave-private m-loop, 2 h-half rounds (R2-verified form) ----
#pragma unroll
        for (int mi = 0; mi < 2; mi++) {
            const int m = 2 * wv + mi;
            const short8 afull = lds_load8(&wtw[m * WTP + l15 * STP + lq * 8]);
            floatx4 d[4];
#pragma unroll
            for (int ct = 0; ct < 4; ct++) d[ct] = (floatx4){0.f, 0.f, 0.f, 0.f};
#pragma unroll
            for (int r = 0; r < 2; r++) {
#pragma unroll
                for (int g2h = 0; g2h < 2; g2h++) {
                    const int g2 = 2 * r + g2h;
                    const int so = (((g2h * 4 + lq) ^ swzh)) * 2;
                    const ushort4 a = g[mi][2 * g2];
                    const ushort4 b = g[mi][2 * g2 + 1];
                    *(unsigned*)&st[(c4 + 0) * STPH + so] = (unsigned)a.x | ((unsigned)b.x << 16);
                    *(unsigned*)&st[(c4 + 1) * STPH + so] = (unsigned)a.y | ((unsigned)b.y << 16);
                    *(unsigned*)&st[(c4 + 2) * STPH + so] = (unsigned)a.z | ((unsigned)b.z << 16);
                    *(unsigned*)&st[(c4 + 3) * STPH + so] = (unsigned)a.w | ((unsigned)b.w << 16);
                }
                const short8 ar = ((lq >> 1) == r) ? afull : zero8;
#pragma unroll
                for (int ct = 0; ct < 4; ct++) {
                    const short8 bfrag =
                        lds_load8(&st[(ct * 16 + l15) * STPH + (((lq & 1) ^ (ct >> 1)) * 8)]);
                    d[ct] = __builtin_amdgcn_mfma_f32_16x16x32_bf16(ar, bfrag, d[ct], 0, 0, 0);
                }
            }
#pragma unroll
            for (int ct = 0; ct < 4; ct++) {
                ushort4 pk;                           // raw weighted (1/cnt in epilogue)
                pk.x = f2bf(d[ct][0]); pk.y = f2bf(d[ct][1]);
                pk.z = f2bf(d[ct][2]); pk.w = f2bf(d[ct][3]);
                *(ushort4*)&wtw[m * WTP + (ct * 16 + l15) * 16 + lq * 4] = pk;
            }
        }
        __syncthreads();   // barrier 1: all 32 weighted rows + inv visible

        // ---- PHASEC: both m-halves, B from 8 named regs; 4-way split-K over kq ----
        {
            float inv8[2][4];
            if (kq == 0) {
#pragma unroll
                for (int mh = 0; mh < 2; mh++)
#pragma unroll
                    for (int r = 0; r < 4; r++)
                        inv8[mh][r] = inv_lds[mh * 16 + lq * 4 + r];   // snapshot
            }
            const unsigned short* const ap0 = &wtw[l15 * WTP + kq * 256 + lq * 8];
            const unsigned short* const ap1 = &wtw[(16 + l15) * WTP + kq * 256 + lq * 8];
            floatx4 acc0 = {0.f, 0.f, 0.f, 0.f};
            floatx4 acc1 = {0.f, 0.f, 0.f, 0.f};
            acc0 = __builtin_amdgcn_mfma_f32_16x16x32_bf16(lds_load8(ap0 + 0 * 32), wf0, acc0, 0, 0, 0);
            acc0 = __builtin_amdgcn_mfma_f32_16x16x32_bf16(lds_load8(ap0 + 1 * 32), wf1, acc0, 0, 0, 0);
            acc0 = __builtin_amdgcn_mfma_f32_16x16x32_bf16(lds_load8(ap0 + 2 * 32), wf2, acc0, 0, 0, 0);
            acc0 = __builtin_amdgcn_mfma_f32_16x16x32_bf16(lds_load8(ap0 + 3 * 32), wf3, acc0, 0, 0, 0);
            acc0 = __builtin_amdgcn_mfma_f32_16x16x32_bf16(lds_load8(ap0 + 4 * 32), wf4, acc0, 0, 0, 0);
            acc0 = __builtin_amdgcn_mfma_f32_16x16x32_bf16(lds_load8(ap0 + 5 * 32), wf5, acc0, 0, 0, 0);
            acc0 = __builtin_amdgcn_mfma_f32_16x16x32_bf16(lds_load8(ap0 + 6 * 32), wf6, acc0, 0, 0, 0);
            acc0 = __builtin_amdgcn_mfma_f32_16x16x32_bf16(lds_load8(ap0 + 7 * 32), wf7, acc0, 0, 0, 0);
            acc1 = __builtin_amdgcn_mfma_f32_16x16x32_bf16(lds_load8(ap1 + 0 * 32), wf0, acc1, 0, 0, 0);
            acc1 = __builtin_amdgcn_mfma_f32_16x16x32_bf16(lds_load8(ap1 + 1 * 32), wf1, acc1, 0, 0, 0);
            acc1 = __builtin_amdgcn_mfma_f32_16x16x32_bf16(lds_load8(ap1 + 2 * 32), wf2, acc1, 0, 0, 0);
            acc1 = __builtin_amdgcn_mfma_f32_16x16x32_bf16(lds_load8(ap1 + 3 * 32), wf3, acc1, 0, 0, 0);
            acc1 = __builtin_amdgcn_mfma_f32_16x16x32_bf16(lds_load8(ap1 + 4 * 32), wf4, acc1, 0, 0, 0);
            acc1 = __builtin_amdgcn_mfma_f32_16x16x32_bf16(lds_load8(ap1 + 5 * 32), wf5, acc1, 0, 0, 0);
            acc1 = __builtin_amdgcn_mfma_f32_16x16x32_bf16(lds_load8(ap1 + 6 * 32), wf6, acc1, 0, 0, 0);
            acc1 = __builtin_amdgcn_mfma_f32_16x16x32_bf16(lds_load8(ap1 + 7 * 32), wf7, acc1, 0, 0, 0);

            if (kq > 0) {
                const int sb = ((kq - 1) * 8 + q * 2) * 256 + l15 * 16 + lq * 4;
                *(floatx4*)&scratch[sb]       = acc0;    // b128, bank-uniform
                *(floatx4*)&scratch[sb + 256] = acc1;
            }
            __syncthreads();   // barrier 2: partials visible; wtw reads drained
            if (kq == 0) {
                const int d = q * 16 + l15;
#pragma unroll
                for (int mh = 0; mh < 2; mh++) {
                    const int sb = (q * 2 + mh) * 256 + l15 * 16 + lq * 4;
                    const floatx4 p1 = *(const floatx4*)&scratch[0 * 2048 + sb];
                    const floatx4 p2 = *(const floatx4*)&scratch[1 * 2048 + sb];
                    const floatx4 p3 = *(const floatx4*)&scratch[2 * 2048 + sb];
                    const floatx4 a = mh ? acc1 : acc0;
#pragma unroll
                    for (int r = 0; r < 4; r++) {
                        const int m = m0 + mh * 16 + lq * 4 + r;
                        if (m < MPTS)
                            out[(size_t)m * 64 + d] =
                                (((a[r] + p1[r]) + (p2[r] + p3[r]))) * inv8[mh][r];
                    }
                }
            }
        }
    }
}

extern "C" void kernel_launch(void* const* d_in, const int* in_sizes, int n_in,
                              void* d_out, int out_size, void* d_ws, size_t ws_size,
                              hipStream_t stream) {
    const float* q_points = (const float*)d_in[0];
    const float* s_points = (const float*)d_in[1];
    const float* s_feats  = (const float*)d_in[2];
    const int*   nbr      = (const int*)d_in[3];
    const float* weights  = (const float*)d_in[4];
    const float* kpts     = (const float*)d_in[5];
    float* out = (float*)d_out;

    char* ws = (char*)d_ws;
    unsigned short* wbf2 = (unsigned short*)ws;              // [0, 131072)
    float4* spts4 = (float4*)(ws + 131072);                  // (N+1)*16 B = 1.6 MB
    float4* kpp = (float4*)(ws + 1731088);                   // 240 B, 16B-aligned
    unsigned short* sfb = (unsigned short*)(ws + 1731584);   // (N+1)*64 bf16 = 12.8 MB

    prep_all<<<815, 256, 0, stream>>>(s_feats, weights, kpts, s_points,
                                      sfb, spts4, wbf2, kpp);
    kpconv_fused<<<PGRID, 1024, 0, stream>>>(q_points, spts4, sfb, nbr,
                                             wbf2, kpp, out);
}

// Round 7
// 145.720 us; speedup vs baseline: 1.0772x; 1.0772x over previous
//
#include <hip/hip_runtime.h>
#include <hip/hip_bf16.h>

#define MPTS 50000
#define NPTS 100000
#define KK 15
#define TM 16      // queries per tile; 8 waves, wave owns 2 -> barrier-free A/B phases
#define NTILES (MPTS / TM)   // 3125
#define PGRID 512            // persistent grid: 2 blocks/CU on 256 CUs (LDS-capped)
#define WTP 1028   // wtw row stride (shorts): 514 b32 = 2 mod 32 -> phase-C A reads uniform banks
#define STP 36     // stage + weight-row stride (shorts): 18 b32 -> all stage ops <=2-way

typedef __attribute__((ext_vector_type(8))) short short8;
typedef __attribute__((ext_vector_type(4))) short short4v;
typedef __attribute__((ext_vector_type(4))) float floatx4;

static __device__ __forceinline__ unsigned short f2bf(float f) {
    __hip_bfloat16 h = __float2bfloat16(f);
    return *reinterpret_cast<unsigned short*>(&h);
}

static __device__ __forceinline__ short8 lds_load8(const unsigned short* p) {
    const short4v a = *(const short4v*)p;
    const short4v b = *(const short4v*)(p + 4);
    short8 r;
    r[0] = a[0]; r[1] = a[1]; r[2] = a[2]; r[3] = a[3];
    r[4] = b[0]; r[5] = b[1]; r[6] = b[2]; r[7] = b[3];
    return r;
}

// ===================== single prep kernel (3 jobs by blockIdx range) ==================
__global__ void prep_all(const float* __restrict__ sf, const float* __restrict__ w,
                         const float* __restrict__ kpts, const float* __restrict__ spt,
                         unsigned short* __restrict__ sfb, float4* __restrict__ spts4,
                         unsigned short* __restrict__ wbf2, float4* __restrict__ kpp) {
    const int b = blockIdx.x, t = threadIdx.x;
    if (b < 782) {
        const int tt = b * 256 + t;
        const int row = tt >> 1, p = tt & 1;          // lane p covers cols 4p+8i+0..3
        if (row < NPTS) {
            const float* base = sf + (size_t)row * 64 + p * 4;
            float4 r = *(const float4*)base;          // i = 0
            {
                ushort4 o;
                o.x = f2bf(r.x); o.y = f2bf(r.y); o.z = f2bf(r.z); o.w = f2bf(r.w);
                *(ushort4*)&sfb[(size_t)row * 64 + p * 4] = o;
            }
#pragma unroll
            for (int i = 1; i < 8; i++) {
                const float4 x = *(const float4*)(base + i * 8);
                ushort4 o;
                o.x = f2bf(x.x); o.y = f2bf(x.y); o.z = f2bf(x.z); o.w = f2bf(x.w);
                *(ushort4*)&sfb[(size_t)row * 64 + i * 8 + p * 4] = o;
                r.x += x.x; r.y += x.y; r.z += x.z; r.w += x.w;   // strict per-j fold
            }
            float sp = (r.x + r.y) + (r.z + r.w);
            sp += __shfl_xor(sp, 1);                  // + other half (commutative: exact)
            if (p == 0) {
                spts4[row] = make_float4(spt[row * 3 + 0], spt[row * 3 + 1],
                                         spt[row * 3 + 2], sp > 0.0f ? 1.0f : -1.0f);
            }
        }
    } else if (b < 814) {
        const int e = (b - 782) * 256 + t;            // 0..8191
        const int lane = e & 63, s = (e >> 6) & 31, wq = e >> 11;
        const int d = wq * 16 + (lane & 15);
        const int lqp = lane >> 4;
        unsigned short o8[8];
#pragma unroll
        for (int j = 0; j < 8; j++) {
            const int kc = s * 32 + lqp * 8 + j;
            const int c = kc >> 4, k = kc & 15;
            o8[j] = (k < KK) ? f2bf(w[k * 4096 + c * 64 + d]) : (unsigned short)0;
        }
#pragma unroll
        for (int j = 0; j < 8; j++) wbf2[(size_t)e * 8 + j] = o8[j];
    } else {
        if (t < 16) *(ushort4*)&sfb[(size_t)NPTS * 64 + t * 4] = make_ushort4(0, 0, 0, 0);
        else if (t == 16) spts4[NPTS] = make_float4(1.0e6f, 1.0e6f, 1.0e6f, -1.0f);
        else if (t >= 32 && t < 32 + KK) {
            const int k = t - 32;
            const float kx = kpts[k * 3 + 0], ky = kpts[k * 3 + 1], kz = kpts[k * 3 + 2];
            kpp[k] = make_float4(-2.f * kx, -2.f * ky, -2.f * kz, kx * kx + ky * ky + kz * kz);
        }
    }
}

// gather one query's 8 row-pair fragments (8 x 8B random loads)
#define GATHER_M(mval)                                                          \
    do {                                                                        \
        const size_t nb_ = (size_t)(m0 + (mval)) * 32;                          \
        int2 ip_;                                                               \
        ip_ = *(const int2*)&nbr[nb_ + 0 + lq * 2];                             \
        g0 = *(const ushort4*)&sfb[(size_t)min(ip_.x, NPTS) * 64 + c4];         \
        g1 = *(const ushort4*)&sfb[(size_t)min(ip_.y, NPTS) * 64 + c4];         \
        ip_ = *(const int2*)&nbr[nb_ + 8 + lq * 2];                             \
        g2 = *(const ushort4*)&sfb[(size_t)min(ip_.x, NPTS) * 64 + c4];         \
        g3 = *(const ushort4*)&sfb[(size_t)min(ip_.y, NPTS) * 64 + c4];         \
        ip_ = *(const int2*)&nbr[nb_ + 16 + lq * 2];                            \
        g4 = *(const ushort4*)&sfb[(size_t)min(ip_.x, NPTS) * 64 + c4];         \
        g5 = *(const ushort4*)&sfb[(size_t)min(ip_.y, NPTS) * 64 + c4];         \
        ip_ = *(const int2*)&nbr[nb_ + 24 + lq * 2];                            \
        g6 = *(const ushort4*)&sfb[(size_t)min(ip_.x, NPTS) * 64 + c4];         \
        g7 = *(const ushort4*)&sfb[(size_t)min(ip_.y, NPTS) * 64 + c4];         \
    } while (0)

// transpose-write one row-pair into stage: b32 slot (g2v*4+lq)^swz -> <=2-way banks
#define STAGE_W(g2v, av, bv)                                                    \
    do {                                                                        \
        const int so_ = (((g2v) * 4 + lq) ^ swzw) * 2;                          \
        *(unsigned*)&st[(c4 + 0) * STP + so_] = (unsigned)(av).x | ((unsigned)(bv).x << 16); \
        *(unsigned*)&st[(c4 + 1) * STP + so_] = (unsigned)(av).y | ((unsigned)(bv).y << 16); \
        *(unsigned*)&st[(c4 + 2) * STP + so_] = (unsigned)(av).z | ((unsigned)(bv).z << 16); \
        *(unsigned*)&st[(c4 + 3) * STP + so_] = (unsigned)(av).w | ((unsigned)(bv).w << 16); \
    } while (0)

// 4 ct MFMAs for query m: weights(A) x staged feats(B) -> weighted rows in wtw
#define PHASEB_MFMA(mval)                                                       \
    do {                                                                        \
        const short8 afrag_ = lds_load8(&wtw[(mval) * WTP + l15 * STP + lq * 8]); \
        _Pragma("unroll")                                                       \
        for (int ct = 0; ct < 4; ct++) {                                        \
            const short8 bfrag_ = lds_load8(&st[(ct * 16 + l15) * STP + ((lq ^ ct) * 8)]); \
            floatx4 d_ = {0.f, 0.f, 0.f, 0.f};                                  \
            d_ = __builtin_amdgcn_mfma_f32_16x16x32_bf16(afrag_, bfrag_, d_, 0, 0, 0); \
            ushort4 pk_;                                                        \
            pk_.x = f2bf(d_[0]); pk_.y = f2bf(d_[1]);                           \
            pk_.z = f2bf(d_[2]); pk_.w = f2bf(d_[3]);                           \
            *(ushort4*)&wtw[(mval) * WTP + (ct * 16 + l15) * 16 + lq * 4] = pk_; \
        }                                                                       \
    } while (0)

// =======================================================================
// Persistent fused kernel: 512 blocks, stride-looped tiles.
// KEY FIX vs R4-R6: __launch_bounds__(512, 2). This toolchain treats the
// 2nd arg as CUDA-style min-BLOCKS/CU (evidence: VGPR hard-capped at 64
// for (512,4)/(512,6)/(1024,4) across three different demand levels).
// (512,2) -> 16 waves/CU -> 4 waves/EU -> 128-VGPR cap: wf0..wf15 (64 regs)
// finally stays RESIDENT. W'' L2 stream 400 MB/pass -> 64 MB one-time.
// LDS: stage 36864 + wtw 32896 + inv 64 + scratch 4096 = 73920 B -> 2 blk/CU.
// =======================================================================
__global__ __launch_bounds__(512, 2) void kpconv_fused(
    const float* __restrict__ q_points,
    const float4* __restrict__ spts4,         // (N+1) {x,y,z, oksign}, row N = (1e6..,-1)
    const unsigned short* __restrict__ sfb,   // (N+1,64) bf16, row N zero
    const int*   __restrict__ nbr,            // (M,32)
    const unsigned short* __restrict__ wbf2,  // lane-linear B frags (128 KB)
    const float4* __restrict__ kpp,           // (15) {-2kx,-2ky,-2kz,|kp|^2}
    float* __restrict__ out)                  // (M,64)
{
    const int t    = threadIdx.x;
    const int lane = t & 63;
    const int wv   = t >> 6;                  // 0..7
    const int l15  = lane & 15;
    const int lq   = lane >> 4;

    __shared__ __align__(16) unsigned short stage[8][64 * STP];   // 36864 B
    __shared__ unsigned short wtw[TM * WTP];                      // 32896 B
    __shared__ float inv_lds[TM];                                 // 64 B
    __shared__ __align__(16) float scratch[1024];                 // 4096 B (dedicated)

    const int mw = 2 * wv + (lane >> 5);
    const int h  = lane & 31;
    const int c4 = l15 * 4;

    // phase-C constants
    const int q  = wv & 3;
    const int kh = wv >> 2;
    const unsigned short* const ap = &wtw[l15 * WTP + kh * 512 + lq * 8];

    // ---- W'' slice -> 16 NAMED registers (64 VGPR), once per persistent block ----
    short8 wf0, wf1, wf2, wf3, wf4, wf5, wf6, wf7;
    short8 wf8, wf9, wf10, wf11, wf12, wf13, wf14, wf15;
    {
        const unsigned short* const bp =
            wbf2 + ((size_t)((q * 32 + kh * 16) * 64) + lane) * 8;
        wf0  = *(const short8*)(bp + 0 * 512);  wf1  = *(const short8*)(bp + 1 * 512);
        wf2  = *(const short8*)(bp + 2 * 512);  wf3  = *(const short8*)(bp + 3 * 512);
        wf4  = *(const short8*)(bp + 4 * 512);  wf5  = *(const short8*)(bp + 5 * 512);
        wf6  = *(const short8*)(bp + 6 * 512);  wf7  = *(const short8*)(bp + 7 * 512);
        wf8  = *(const short8*)(bp + 8 * 512);  wf9  = *(const short8*)(bp + 9 * 512);
        wf10 = *(const short8*)(bp + 10 * 512); wf11 = *(const short8*)(bp + 11 * 512);
        wf12 = *(const short8*)(bp + 12 * 512); wf13 = *(const short8*)(bp + 13 * 512);
        wf14 = *(const short8*)(bp + 14 * 512); wf15 = *(const short8*)(bp + 15 * 512);
    }

    unsigned short* const st = stage[wv];
    const int swzw = (l15 >> 2) << 2;

    for (int tile = blockIdx.x; tile < NTILES; tile += PGRID) {
        const int m0 = tile * TM;
        const int ma = 2 * wv, mb = 2 * wv + 1;

        // ---- PREFETCH: neighbor idx + point gather + query ma's features ----
        const int idxp = nbr[(size_t)(m0 + mw) * 32 + h];
        const float4 sp4 = spts4[min(idxp, NPTS)];
        ushort4 g0, g1, g2, g3, g4, g5, g6, g7;
        GATHER_M(ma);

        // ---- WEIGHTS: kernel-point weights + neighbor count (covers gather latency) ----
        {
            const float rx = sp4.x - q_points[(m0 + mw) * 3 + 0];
            const float ry = sp4.y - q_points[(m0 + mw) * 3 + 1];
            const float rz = sp4.z - q_points[(m0 + mw) * 3 + 2];
            const float r2 = rx * rx + ry * ry + rz * rz;
            unsigned short* wrow = &wtw[mw * WTP];
#pragma unroll
            for (int k = 0; k < KK; k++) {
                const float4 kp = kpp[k];             // wave-uniform -> s_load
                float d2 = kp.w;
                d2 = fmaf(rx, kp.x, d2);
                d2 = fmaf(ry, kp.y, d2);
                d2 = fmaf(rz, kp.z, d2);
                d2 = fmaxf(r2 + d2, 0.0f);            // guard tiny-negative from rounding
                const float wv_ = fmaxf(fmaf(-0.5f, __builtin_amdgcn_sqrtf(d2), 1.0f), 0.0f);
                wrow[k * STP + h] = f2bf(wv_);
            }
            wrow[15 * STP + h] = 0;                   // k-pad row

            const unsigned long long bal = __ballot(sp4.w > 0.0f);
            if (h == 0) {
                const int cnt = __popc((unsigned)(bal >> ((lane >> 5) * 32)));
                inv_lds[mw] = 1.0f / (float)(cnt < 1 ? 1 : cnt);
            }
        }

        // ---- PHASEB(ma): stage ma; issue mb gathers EARLY (hide under ma MFMAs) ----
        STAGE_W(0, g0, g1);
        STAGE_W(1, g2, g3);
        STAGE_W(2, g4, g5);
        STAGE_W(3, g6, g7);
        GATHER_M(mb);                                  // in flight across ma's MFMAs
        PHASEB_MFMA(ma);

        // ---- PHASEB(mb) ----
        STAGE_W(0, g0, g1);
        STAGE_W(1, g2, g3);
        STAGE_W(2, g4, g5);
        STAGE_W(3, g6, g7);
        PHASEB_MFMA(mb);

        __syncthreads();   // barrier 1: weighted rows + inv visible

        // ---- PHASEC: out = inv * weighted x W'' (B from resident regs; split-K) ----
        {
            float inv4[4];
            if (kh == 0) {
#pragma unroll
                for (int r = 0; r < 4; r++) inv4[r] = inv_lds[lq * 4 + r];  // snapshot
            }
            floatx4 acc = {0.f, 0.f, 0.f, 0.f};
            acc = __builtin_amdgcn_mfma_f32_16x16x32_bf16(lds_load8(ap + 0 * 32),  wf0,  acc, 0, 0, 0);
            acc = __builtin_amdgcn_mfma_f32_16x16x32_bf16(lds_load8(ap + 1 * 32),  wf1,  acc, 0, 0, 0);
            acc = __builtin_amdgcn_mfma_f32_16x16x32_bf16(lds_load8(ap + 2 * 32),  wf2,  acc, 0, 0, 0);
            acc = __builtin_amdgcn_mfma_f32_16x16x32_bf16(lds_load8(ap + 3 * 32),  wf3,  acc, 0, 0, 0);
            acc = __builtin_amdgcn_mfma_f32_16x16x32_bf16(lds_load8(ap + 4 * 32),  wf4,  acc, 0, 0, 0);
            acc = __builtin_amdgcn_mfma_f32_16x16x32_bf16(lds_load8(ap + 5 * 32),  wf5,  acc, 0, 0, 0);
            acc = __builtin_amdgcn_mfma_f32_16x16x32_bf16(lds_load8(ap + 6 * 32),  wf6,  acc, 0, 0, 0);
            acc = __builtin_amdgcn_mfma_f32_16x16x32_bf16(lds_load8(ap + 7 * 32),  wf7,  acc, 0, 0, 0);
            acc = __builtin_amdgcn_mfma_f32_16x16x32_bf16(lds_load8(ap + 8 * 32),  wf8,  acc, 0, 0, 0);
            acc = __builtin_amdgcn_mfma_f32_16x16x32_bf16(lds_load8(ap + 9 * 32),  wf9,  acc, 0, 0, 0);
            acc = __builtin_amdgcn_mfma_f32_16x16x32_bf16(lds_load8(ap + 10 * 32), wf10, acc, 0, 0, 0);
            acc = __builtin_amdgcn_mfma_f32_16x16x32_bf16(lds_load8(ap + 11 * 32), wf11, acc, 0, 0, 0);
            acc = __builtin_amdgcn_mfma_f32_16x16x32_bf16(lds_load8(ap + 12 * 32), wf12, acc, 0, 0, 0);
            acc = __builtin_amdgcn_mfma_f32_16x16x32_bf16(lds_load8(ap + 13 * 32), wf13, acc, 0, 0, 0);
            acc = __builtin_amdgcn_mfma_f32_16x16x32_bf16(lds_load8(ap + 14 * 32), wf14, acc, 0, 0, 0);
            acc = __builtin_amdgcn_mfma_f32_16x16x32_bf16(lds_load8(ap + 15 * 32), wf15, acc, 0, 0, 0);

            if (kh == 1) {
                *(floatx4*)&scratch[q * 256 + l15 * 16 + lq * 4] = acc;   // b128, uniform banks
            }
            __syncthreads();   // barrier 2: partials visible; wtw reads drained
            if (kh == 0) {
                const floatx4 p = *(const floatx4*)&scratch[q * 256 + l15 * 16 + lq * 4];
                const int d = q * 16 + l15;
#pragma unroll
                for (int r = 0; r < 4; r++) {
                    const int m = lq * 4 + r;
                    out[(size_t)(m0 + m) * 64 + d] = (acc[r] + p[r]) * inv4[r];
                }
            }
        }
    }
}

extern "C" void kernel_launch(void* const* d_in, const int* in_sizes, int n_in,
                              void* d_out, int out_size, void* d_ws, size_t ws_size,
                              hipStream_t stream) {
    const float* q_points = (const float*)d_in[0];
    const float* s_points = (const float*)d_in[1];
    const float* s_feats  = (const float*)d_in[2];
    const int*   nbr      = (const int*)d_in[3];
    const float* weights  = (const float*)d_in[4];
    const float* kpts     = (const float*)d_in[5];
    float* out = (float*)d_out;

    char* ws = (char*)d_ws;
    unsigned short* wbf2 = (unsigned short*)ws;              // [0, 131072)
    float4* spts4 = (float4*)(ws + 131072);                  // (N+1)*16 B = 1.6 MB
    float4* kpp = (float4*)(ws + 1731088);                   // 240 B, 16B-aligned
    unsigned short* sfb = (unsigned short*)(ws + 1731584);   // (N+1)*64 bf16 = 12.8 MB

    prep_all<<<815, 256, 0, stream>>>(s_feats, weights, kpts, s_points,
                                      sfb, spts4, wbf2, kpp);
    kpconv_fused<<<PGRID, 512, 0, stream>>>(q_points, spts4, sfb, nbr,
                                            wbf2, kpp, out);
}

// Round 8
// 132.051 us; speedup vs baseline: 1.1888x; 1.1035x over previous
//
#include <hip/hip_runtime.h>
#include <hip/hip_bf16.h>

#define MPTS 50000
#define NPTS 100000
#define KK 15
#define TM 16      // queries per tile; 8 waves, wave owns 2 -> barrier-free A/B phases
#define WTP 1028   // wtw row stride (shorts): 514 b32 = 2 mod 32 -> phase-C A reads uniform banks
#define STP 36     // weight-row stride inside wtw (shorts)
#define STPH 20    // half-h stage row stride (shorts): 40 B rows (8B-aligned)

typedef __attribute__((ext_vector_type(8))) short short8;
typedef __attribute__((ext_vector_type(4))) short short4v;
typedef __attribute__((ext_vector_type(4))) float floatx4;

static __device__ __forceinline__ unsigned short f2bf(float f) {
    __hip_bfloat16 h = __float2bfloat16(f);
    return *reinterpret_cast<unsigned short*>(&h);
}

static __device__ __forceinline__ short8 lds_load8(const unsigned short* p) {
    const short4v a = *(const short4v*)p;
    const short4v b = *(const short4v*)(p + 4);
    short8 r;
    r[0] = a[0]; r[1] = a[1]; r[2] = a[2]; r[3] = a[3];
    r[4] = b[0]; r[5] = b[1]; r[6] = b[2]; r[7] = b[3];
    return r;
}

// exact bf16 of a signed-byte integer (|v|<=127 -> no rounding)
static __device__ __forceinline__ unsigned cvtb(unsigned char u) {
    return (unsigned)f2bf((float)(int)(signed char)u);
}

// ===================== single prep kernel (3 jobs by blockIdx range) ==================
// [0,782):   s_feats rows -> i8 quantized sfb8 (64 B/row) + rowsum (exact pairwise order)
//            + per-row scale; spts4[row] = {x,y,z, rowsum>0 ? scale : -scale}
// [782,814): wbf2 lane-linear B frags (128 KB)
// 814:       tail: zero sfb8 row N, spts4[N]=(1e6,1e6,1e6,-1), kpp
__global__ void prep_all(const float* __restrict__ sf, const float* __restrict__ w,
                         const float* __restrict__ kpts, const float* __restrict__ spt,
                         unsigned char* __restrict__ sfb8, float4* __restrict__ spts4,
                         unsigned short* __restrict__ wbf2, float4* __restrict__ kpp) {
    const int b = blockIdx.x, t = threadIdx.x;
    if (b < 782) {
        const int tt = b * 256 + t;
        const int row = tt >> 1, p = tt & 1;          // lane p covers cols 4p+8i+0..3
        if (row < NPTS) {
            const float* base = sf + (size_t)row * 64 + p * 4;
            float4 x[8];
            x[0] = *(const float4*)base;
            float4 r = x[0];
            float am = fmaxf(fmaxf(fabsf(x[0].x), fabsf(x[0].y)),
                             fmaxf(fabsf(x[0].z), fabsf(x[0].w)));
#pragma unroll
            for (int i = 1; i < 8; i++) {
                x[i] = *(const float4*)(base + i * 8);
                r.x += x[i].x; r.y += x[i].y; r.z += x[i].z; r.w += x[i].w; // strict fold
                am = fmaxf(am, fmaxf(fmaxf(fabsf(x[i].x), fabsf(x[i].y)),
                                     fmaxf(fabsf(x[i].z), fabsf(x[i].w))));
            }
            float sp = (r.x + r.y) + (r.z + r.w);
            sp += __shfl_xor(sp, 1);                  // + other half (commutative: exact)
            am = fmaxf(am, __shfl_xor(am, 1));        // row absmax (commutative: exact)
            const float inv = am > 0.0f ? 127.0f / am : 0.0f;
#pragma unroll
            for (int i = 0; i < 8; i++) {
                uchar4 o;
                o.x = (unsigned char)(int)rintf(x[i].x * inv);
                o.y = (unsigned char)(int)rintf(x[i].y * inv);
                o.z = (unsigned char)(int)rintf(x[i].z * inv);
                o.w = (unsigned char)(int)rintf(x[i].w * inv);
                *(uchar4*)&sfb8[(size_t)row * 64 + i * 8 + p * 4] = o;
            }
            if (p == 0) {
                const float sc = am * (1.0f / 127.0f);
                spts4[row] = make_float4(spt[row * 3 + 0], spt[row * 3 + 1],
                                         spt[row * 3 + 2], sp > 0.0f ? sc : -sc);
            }
        }
    } else if (b < 814) {
        const int e = (b - 782) * 256 + t;            // 0..8191
        const int lane = e & 63, s = (e >> 6) & 31, wq = e >> 11;
        const int d = wq * 16 + (lane & 15);
        const int lqp = lane >> 4;
        unsigned short o8[8];
#pragma unroll
        for (int j = 0; j < 8; j++) {
            const int kc = s * 32 + lqp * 8 + j;
            const int c = kc >> 4, k = kc & 15;
            o8[j] = (k < KK) ? f2bf(w[k * 4096 + c * 64 + d]) : (unsigned short)0;
        }
#pragma unroll
        for (int j = 0; j < 8; j++) wbf2[(size_t)e * 8 + j] = o8[j];
    } else {
        if (t < 16) *(uchar4*)&sfb8[(size_t)NPTS * 64 + t * 4] = make_uchar4(0, 0, 0, 0);
        else if (t == 16) spts4[NPTS] = make_float4(1.0e6f, 1.0e6f, 1.0e6f, -1.0f);
        else if (t >= 32 && t < 32 + KK) {
            const int k = t - 32;
            const float kx = kpts[k * 3 + 0], ky = kpts[k * 3 + 1], kz = kpts[k * 3 + 2];
            kpp[k] = make_float4(-2.f * kx, -2.f * ky, -2.f * kz, kx * kx + ky * ky + kz * kz);
        }
    }
}

// =======================================================================
// Fused main kernel (R2 structure + int8 features). TM=16, 512 threads.
// Features gathered as 64 B i8 rows (footprint 6.4 MB: ~2x L2 hit rate,
// half the gather bytes). Dequant is EXACT: B frag = bf16(int8); per-row
// scale folded into A: bf16(w_kh * s_h). LDS: stage 20480 + wtw 32896 +
// inv 64 = 53440 B -> up to 3 blocks/CU; scratch aliases stage (safe:
// phase B never touches stage after barrier 1, kernel ends after C).
// =======================================================================
__global__ __launch_bounds__(512, 2) void kpconv_fused(
    const float* __restrict__ q_points,
    const float4* __restrict__ spts4,         // (N+1) {x,y,z, +-scale}, row N = (1e6..,-1)
    const unsigned char* __restrict__ sfb8,   // (N+1,64) i8, row N zero
    const int*   __restrict__ nbr,            // (M,32)
    const unsigned short* __restrict__ wbf2,  // lane-linear B frags (128 KB)
    const float4* __restrict__ kpp,           // (15) {-2kx,-2ky,-2kz,|kp|^2}
    float* __restrict__ out)                  // (M,64)
{
    const int t    = threadIdx.x;
    const int m0   = blockIdx.x * TM;
    const int lane = t & 63;
    const int wv   = t >> 6;                  // 0..7
    const int l15  = lane & 15;
    const int lq   = lane >> 4;

    __shared__ __align__(16) unsigned short stage[8][64 * STPH];  // 20480 B
    __shared__ unsigned short wtw[TM * WTP];                      // 32896 B
    __shared__ float inv_lds[TM];

    const int mw = 2 * wv + (lane >> 5);
    const int h  = lane & 31;
    const int c4 = l15 * 4;                   // byte col in i8 row AND stage channel row

    // ---- per-lane neighbor index + merged point/scale gather ----
    const int idxp = nbr[(size_t)(m0 + mw) * 32 + h];
    const float4 sp4 = spts4[min(idxp, NPTS)];

    // ---- issue BOTH m feature gathers (16 x 4B i8, rows paired per lane slot) ----
    uchar4 g[2][8];
#pragma unroll
    for (int mi = 0; mi < 2; mi++) {
        const int m = 2 * wv + mi;
#pragma unroll
        for (int g2 = 0; g2 < 4; g2++) {
            const int r0 = g2 * 8 + lq * 2;
            const int2 ip = *(const int2*)&nbr[(size_t)(m0 + m) * 32 + r0];
            const int i0 = min(ip.x, NPTS);
            const int i1 = min(ip.y, NPTS);
            g[mi][2 * g2]     = *(const uchar4*)&sfb8[(size_t)i0 * 64 + c4];
            g[mi][2 * g2 + 1] = *(const uchar4*)&sfb8[(size_t)i1 * 64 + c4];
        }
    }

    // ---- kernel-point weights (x per-row scale) + counts ----
    {
        const float rx = sp4.x - q_points[(m0 + mw) * 3 + 0];
        const float ry = sp4.y - q_points[(m0 + mw) * 3 + 1];
        const float rz = sp4.z - q_points[(m0 + mw) * 3 + 2];
        const float r2 = rx * rx + ry * ry + rz * rz;
        const float ss = fabsf(sp4.w);        // per-row dequant scale
        unsigned short* wrow = &wtw[mw * WTP];
#pragma unroll
        for (int k = 0; k < KK; k++) {
            const float4 kp = kpp[k];                 // wave-uniform -> s_load
            float d2 = kp.w;
            d2 = fmaf(rx, kp.x, d2);
            d2 = fmaf(ry, kp.y, d2);
            d2 = fmaf(rz, kp.z, d2);
            d2 = fmaxf(r2 + d2, 0.0f);                // guard tiny-negative from rounding
            const float wv_ = fmaxf(fmaf(-0.5f, __builtin_amdgcn_sqrtf(d2), 1.0f), 0.0f);
            wrow[k * STP + h] = f2bf(wv_ * ss);       // scale folded into A
        }
        wrow[15 * STP + h] = 0;                       // k-pad row

        const unsigned long long bal = __ballot(sp4.w > 0.0f);  // -0.0 > 0 is false
        if (h == 0) {
            const int cnt = __popc((unsigned)(bal >> ((lane >> 5) * 32)));
            inv_lds[mw] = 1.0f / (float)(cnt < 1 ? 1 : cnt);
        }
    }

    // ---- wave-private m-loop, 2 h-half rounds each (half stage, i8->bf16 in stage) ----
    unsigned short* const st = stage[wv];
    const int swzh = (l15 >> 3) << 2;                 // flips slot bit2 for rows c >= 32
    const short8 zero8 = {0, 0, 0, 0, 0, 0, 0, 0};
#pragma unroll
    for (int mi = 0; mi < 2; mi++) {
        const int m = 2 * wv + mi;
        const short8 afull = lds_load8(&wtw[m * WTP + l15 * STP + lq * 8]);
        floatx4 d[4];
#pragma unroll
        for (int ct = 0; ct < 4; ct++) d[ct] = (floatx4){0.f, 0.f, 0.f, 0.f};
#pragma unroll
        for (int r = 0; r < 2; r++) {
#pragma unroll
            for (int g2h = 0; g2h < 2; g2h++) {
                const int g2 = 2 * r + g2h;
                const int so = (((g2h * 4 + lq) ^ swzh)) * 2;
                const uchar4 a = g[mi][2 * g2];
                const uchar4 b = g[mi][2 * g2 + 1];
                *(unsigned*)&st[(c4 + 0) * STPH + so] = cvtb(a.x) | (cvtb(b.x) << 16);
                *(unsigned*)&st[(c4 + 1) * STPH + so] = cvtb(a.y) | (cvtb(b.y) << 16);
                *(unsigned*)&st[(c4 + 2) * STPH + so] = cvtb(a.z) | (cvtb(b.z) << 16);
                *(unsigned*)&st[(c4 + 3) * STPH + so] = cvtb(a.w) | (cvtb(b.w) << 16);
            }
            const short8 ar = ((lq >> 1) == r) ? afull : zero8;
#pragma unroll
            for (int ct = 0; ct < 4; ct++) {
                const short8 bfrag =
                    lds_load8(&st[(ct * 16 + l15) * STPH + (((lq & 1) ^ (ct >> 1)) * 8)]);
                d[ct] = __builtin_amdgcn_mfma_f32_16x16x32_bf16(ar, bfrag, d[ct], 0, 0, 0);
            }
        }
#pragma unroll
        for (int ct = 0; ct < 4; ct++) {
            ushort4 pk;                               // raw weighted (1/cnt in epilogue)
            pk.x = f2bf(d[ct][0]); pk.y = f2bf(d[ct][1]);
            pk.z = f2bf(d[ct][2]); pk.w = f2bf(d[ct][3]);
            *(ushort4*)&wtw[m * WTP + (ct * 16 + l15) * 16 + lq * 4] = pk;
        }
    }
    __syncthreads();   // barrier 1: all 16 weighted rows + inv visible

    // ---- Phase C: out[m][d] = inv[m] * sum_kc weighted[m][kc] * W''[kc][d] ----
    {
        const int q  = wv & 3;
        const int kh = wv >> 2;
        floatx4 acc = {0.f, 0.f, 0.f, 0.f};
        const unsigned short* ap = &wtw[l15 * WTP + kh * 512 + lq * 8];
        const unsigned short* bp = wbf2 + ((size_t)((q * 32 + kh * 16) * 64) + lane) * 8;
#pragma unroll 8
        for (int s = 0; s < 16; s++) {
            const short8 a = lds_load8(ap + s * 32);
            const short8 b = *(const short8*)(bp + s * 512);   // coalesced, L2-hot
            acc = __builtin_amdgcn_mfma_f32_16x16x32_bf16(a, b, acc, 0, 0, 0);
        }

        // split-K reduction through the dead stage region (4 KB; safe: kernel ends)
        float* const scratch = (float*)&stage[0][0];
        if (kh == 1) {
            *(floatx4*)&scratch[q * 256 + l15 * 16 + lq * 4] = acc;   // b128, uniform banks
        }
        __syncthreads();   // barrier 2: partials visible
        if (kh == 0) {
            const floatx4 p = *(const floatx4*)&scratch[q * 256 + l15 * 16 + lq * 4];
            const int d = q * 16 + l15;
#pragma unroll
            for (int r = 0; r < 4; r++) {
                const int m = lq * 4 + r;
                out[(size_t)(m0 + m) * 64 + d] = (acc[r] + p[r]) * inv_lds[m];
            }
        }
    }
}

extern "C" void kernel_launch(void* const* d_in, const int* in_sizes, int n_in,
                              void* d_out, int out_size, void* d_ws, size_t ws_size,
                              hipStream_t stream) {
    const float* q_points = (const float*)d_in[0];
    const float* s_points = (const float*)d_in[1];
    const float* s_feats  = (const float*)d_in[2];
    const int*   nbr      = (const int*)d_in[3];
    const float* weights  = (const float*)d_in[4];
    const float* kpts     = (const float*)d_in[5];
    float* out = (float*)d_out;

    char* ws = (char*)d_ws;
    unsigned short* wbf2 = (unsigned short*)ws;              // [0, 131072)
    float4* spts4 = (float4*)(ws + 131072);                  // (N+1)*16 B = 1.6 MB
    float4* kpp = (float4*)(ws + 1731088);                   // 240 B, 16B-aligned
    unsigned char* sfb8 = (unsigned char*)(ws + 1731584);    // (N+1)*64 i8 = 6.4 MB

    prep_all<<<815, 256, 0, stream>>>(s_feats, weights, kpts, s_points,
                                      sfb8, spts4, wbf2, kpp);
    kpconv_fused<<<MPTS / TM, 512, 0, stream>>>(q_points, spts4, sfb8, nbr,
                                                wbf2, kpp, out);
}